// Round 2
// baseline (563.268 us; speedup 1.0000x reference)
//
#include <hip/hip_runtime.h>

// Problem constants
#define EPS 1e-5f
#define B_ 4
#define N_ 8192
#define D_ 1024
#define H_ 8
#define HD_ 128
#define M_TOT 32768   // B*N
#define NQKV 3072     // 3*D

typedef __bf16 bf16x8 __attribute__((ext_vector_type(8)));
typedef float f32x4 __attribute__((ext_vector_type(4)));

__device__ __forceinline__ float bf2f(unsigned short u) {
    unsigned int v = ((unsigned int)u) << 16;
    return __uint_as_float(v);
}
__device__ __forceinline__ unsigned short f2bf(float f) {
    unsigned int u = __float_as_uint(f);
    u += 0x7fffu + ((u >> 16) & 1u);   // RNE
    return (unsigned short)(u >> 16);
}

// fast activations: v_exp_f32 + v_rcp_f32 (~1e-6 rel err, saturates correctly)
__device__ __forceinline__ float fast_sigmoid(float v) {
    return __builtin_amdgcn_rcpf(1.0f + __expf(-v));
}
__device__ __forceinline__ float fast_tanh(float v) {
    return 1.0f - 2.0f * __builtin_amdgcn_rcpf(1.0f + __expf(2.0f * v));
}

// async global->LDS, 16B per lane; LDS dest is wave-uniform base + lane*16
__device__ __forceinline__ void gl_lds16(const void* g, void* l) {
    __builtin_amdgcn_global_load_lds(
        (const __attribute__((address_space(1))) unsigned int*)g,
        (__attribute__((address_space(3))) unsigned int*)l, 16, 0, 0);
}

// ---------------- Kernel 1: LayerNorm -> bf16 xn [32768][1024] ----------------
__global__ __launch_bounds__(256) void ln_kernel(const float* __restrict__ x,
                                                 const float* __restrict__ gamma,
                                                 const float* __restrict__ beta,
                                                 unsigned short* __restrict__ xn) {
    const int row = blockIdx.x;
    const int t = threadIdx.x;
    const float* xr = x + (size_t)row * D_;
    float4 xv = ((const float4*)xr)[t];                       // 4 elems/thread
    float s = xv.x + xv.y + xv.z + xv.w;
    float s2 = xv.x * xv.x + xv.y * xv.y + xv.z * xv.z + xv.w * xv.w;
    for (int off = 32; off > 0; off >>= 1) {
        s += __shfl_down(s, off);
        s2 += __shfl_down(s2, off);
    }
    __shared__ float red[8];
    if ((t & 63) == 0) { red[t >> 6] = s; red[4 + (t >> 6)] = s2; }
    __syncthreads();
    float ts = red[0] + red[1] + red[2] + red[3];
    float ts2 = red[4] + red[5] + red[6] + red[7];
    float mu = ts * (1.0f / D_);
    float var = ts2 * (1.0f / D_) - mu * mu;
    float rs = rsqrtf(var + EPS);
    float4 g = ((const float4*)gamma)[t];
    float4 bt = ((const float4*)beta)[t];
    ushort4 o;
    o.x = f2bf((xv.x - mu) * rs * g.x + bt.x);
    o.y = f2bf((xv.y - mu) * rs * g.y + bt.y);
    o.z = f2bf((xv.z - mu) * rs * g.z + bt.z);
    o.w = f2bf((xv.w - mu) * rs * g.w + bt.w);
    ((ushort4*)(xn + (size_t)row * D_))[t] = o;
}

// ---------------- Kernel 2: transpose+cast w [1024][3072] -> wT bf16 [3072][1024]
__global__ __launch_bounds__(256) void wt_kernel(const float* __restrict__ w,
                                                 unsigned short* __restrict__ wT) {
    __shared__ float tile[64][65];
    const int n0 = blockIdx.x * 64;   // 48 blocks
    const int k0 = blockIdx.y * 64;   // 16 blocks
    const int t = threadIdx.x;
    const int tx = t & 63, ty = t >> 6;
    #pragma unroll
    for (int i = 0; i < 16; i++) {
        int r = i * 4 + ty;
        tile[r][tx] = w[(size_t)(k0 + r) * NQKV + n0 + tx];
    }
    __syncthreads();
    #pragma unroll
    for (int i = 0; i < 16; i++) {
        int r = i * 4 + ty;
        wT[(size_t)(n0 + r) * D_ + k0 + tx] = f2bf(tile[tx][r]);
    }
}

// ---------------- Kernel 3: fused QKV GEMM, 256x256 tile, 8-phase pipeline ----
// 8 waves (2M x 4N), per-wave 128x64 output, BK=64, double-buffered 128KB LDS.
// T2: LDS XOR-swizzle via pre-swizzled global source + XOR'd ds_read offsets.
// T3/T4 (deepened vs round 1): stage BOTH halves of next K-tile's B at the
//   phase where Bbuf frees (p2/p6) and both A halves one phase later (p3/p7).
//   Youngest-needed load is issued 4-5 phases before its wait (~700 cy cover).
//   Waits are s_waitcnt vmcnt(8): the next-next K-tile (8 loads) stays in
//   flight across the wait; never drained to 0 until the tail.
// T5: setprio(1) around each 16-MFMA quadrant cluster.

#define BAR()   asm volatile("s_barrier" ::: "memory")
#define VM8()   asm volatile("s_waitcnt vmcnt(8)" ::: "memory")
#define VM0()   asm volatile("s_waitcnt vmcnt(0)" ::: "memory")

// stage half h (0/1) of a 256x64 tile (K-tile ktv) into LDS tile base.
// srcB: per-thread pre-swizzled source base; dest linear (HW: base + lane*16).
#define STAGE(dstTile, srcB, h, ktv) do {                                   \
    const char* s0_ = (srcB) + (size_t)(h) * 262144 + (size_t)(ktv) * 128;  \
    char* d0_ = (dstTile) + (h) * 16384 + w * 1024;                         \
    gl_lds16(s0_, d0_);                                                     \
    gl_lds16(s0_ + 131072, d0_ + 8192);                                     \
} while (0)

// load A fragments for quadrant-half mhv (4 mi x 2 ks), swizzled read
#define LDA(Ab, mhv) do {                                                   \
    _Pragma("unroll") for (int i_ = 0; i_ < 4; i_++) {                      \
        const char* rp_ = (Ab) + (size_t)(wm + (mhv) * 64 + i_ * 16 + ln16) * 128; \
        af[i_][0] = *(const bf16x8*)(rp_ + kc0);                            \
        af[i_][1] = *(const bf16x8*)(rp_ + kc1);                            \
    } } while (0)

// load B fragments for quadrant-half nhv (2 ni x 2 ks)
#define LDB(Bb, nhv) do {                                                   \
    _Pragma("unroll") for (int j_ = 0; j_ < 2; j_++) {                      \
        const char* rp_ = (Bb) + (size_t)(wn + (nhv) * 32 + j_ * 16 + ln16) * 128; \
        bfr[nhv][j_][0] = *(const bf16x8*)(rp_ + kc0);                      \
        bfr[nhv][j_][1] = *(const bf16x8*)(rp_ + kc1);                      \
    } } while (0)

// one C-quadrant (4 mi x 2 ni x 2 ks = 16 MFMA) bracketed by setprio
#define MFMAQ(mhv, nhv) do {                                                \
    __builtin_amdgcn_s_setprio(1);                                          \
    _Pragma("unroll") for (int i_ = 0; i_ < 4; i_++)                        \
    _Pragma("unroll") for (int j_ = 0; j_ < 2; j_++) {                      \
        f32x4* ap_ = &acc[(mhv) * 4 + i_][(nhv) * 2 + j_];                  \
        *ap_ = __builtin_amdgcn_mfma_f32_16x16x32_bf16(af[i_][0], bfr[nhv][j_][0], *ap_, 0, 0, 0); \
        *ap_ = __builtin_amdgcn_mfma_f32_16x16x32_bf16(af[i_][1], bfr[nhv][j_][1], *ap_, 0, 0, 0); \
    }                                                                       \
    __builtin_amdgcn_s_setprio(0);                                          \
} while (0)

__global__ __launch_bounds__(512, 2) void qkv_gemm(const unsigned short* __restrict__ xn,
                                                   const unsigned short* __restrict__ wT,
                                                   const int* __restrict__ mask,
                                                   unsigned short* __restrict__ qws,
                                                   unsigned short* __restrict__ kT,
                                                   unsigned short* __restrict__ vT) {
    __shared__ __align__(16) char smem[131072];
    const int t = threadIdx.x;
    const int w = t >> 6, l = t & 63;
    const int quad = l >> 4, ln16 = l & 15;

    // XCD-aware swizzle: 1536 blocks, 1536 % 8 == 0 -> simple form is bijective.
    // Consecutive blocks on one XCD share mt -> A-tile L2 reuse.
    const int lin = blockIdx.x;
    const int swz = (lin & 7) * 192 + (lin >> 3);
    const int mt = swz / 12, nt = swz - mt * 12;
    const int m0 = mt * 256, n0 = nt * 256;
    const int wm = (w >> 2) * 128, wn = (w & 3) * 64;

    char* Abuf0 = smem;
    char* Bbuf0 = smem + 32768;
    char* Abuf1 = smem + 65536;
    char* Bbuf1 = smem + 98304;

    // staging: lane covers dest row (w*8 + l>>3), granule (l&7).
    // stored-swizzled: LDS[row][g] = G[row][g ^ (row&7)]; row&7 == l>>3
    const int gsw = (l & 7) ^ (l >> 3);
    const char* aSrc = (const char*)xn + ((size_t)(m0 + w * 8 + (l >> 3)) * 2048) + gsw * 16;
    const char* bSrc = (const char*)wT + ((size_t)(n0 + w * 8 + (l >> 3)) * 2048) + gsw * 16;

    // ds_read swizzled granule offsets for ks=0/1 (row&7 == ln16&7)
    const int r7 = ln16 & 7;
    const int kc0 = ((quad ^ r7) << 4);
    const int kc1 = (((4 | quad) ^ r7) << 4);

    f32x4 acc[8][4] = {};
    bf16x8 af[4][2];
    bf16x8 bfr[2][2][2];

    // prologue: kt0 + kt1 fully staged (16 loads); wait kt0 landed, kt1 in flight
    STAGE(Bbuf0, bSrc, 0, 0); STAGE(Bbuf0, bSrc, 1, 0);
    STAGE(Abuf0, aSrc, 0, 0); STAGE(Abuf0, aSrc, 1, 0);
    STAGE(Bbuf1, bSrc, 0, 1); STAGE(Bbuf1, bSrc, 1, 1);
    STAGE(Abuf1, aSrc, 0, 1); STAGE(Abuf1, aSrc, 1, 1);
    VM8();
    BAR();

    for (int itn = 0; itn < 8; ++itn) {
        const int kt2 = 2 * itn + 2, kt3 = 2 * itn + 3;
        const bool pf = (itn < 7);

        // p0: read buf0 A(mh0)+B(nh0)
        LDA(Abuf0, 0); LDB(Bbuf0, 0);
        BAR(); MFMAQ(0, 0); BAR();

        // p1: read buf0 B(nh1)   [Bbuf0 fully read after this phase]
        LDB(Bbuf0, 1);
        BAR(); MFMAQ(0, 1); BAR();

        // p2: stage BOTH B(kt2) halves -> Bbuf0 (freed); read buf0 A(mh1)
        if (pf) { STAGE(Bbuf0, bSrc, 0, kt2); STAGE(Bbuf0, bSrc, 1, kt2); }
        LDA(Abuf0, 1);
        BAR(); MFMAQ(1, 0); BAR();

        // p3: stage BOTH A(kt2) halves -> Abuf0 (freed); wait kt1 landed (kt2 stays in flight)
        if (pf) { STAGE(Abuf0, aSrc, 0, kt2); STAGE(Abuf0, aSrc, 1, kt2); }
        BAR(); MFMAQ(1, 1);
        if (pf) { VM8(); } else { VM0(); }
        BAR();

        // p4: read buf1 A(mh0)+B(nh0)
        LDA(Abuf1, 0); LDB(Bbuf1, 0);
        BAR(); MFMAQ(0, 0); BAR();

        // p5: read buf1 B(nh1)   [Bbuf1 fully read after this phase]
        LDB(Bbuf1, 1);
        BAR(); MFMAQ(0, 1); BAR();

        // p6: stage BOTH B(kt3) halves -> Bbuf1 (freed); read buf1 A(mh1)
        if (pf) { STAGE(Bbuf1, bSrc, 0, kt3); STAGE(Bbuf1, bSrc, 1, kt3); }
        LDA(Abuf1, 1);
        BAR(); MFMAQ(1, 0); BAR();

        // p7: stage BOTH A(kt3) halves -> Abuf1 (freed); wait kt2 landed (kt3 in flight)
        if (pf) { STAGE(Abuf1, aSrc, 0, kt3); STAGE(Abuf1, aSrc, 1, kt3); }
        BAR(); MFMAQ(1, 1);
        if (pf) { VM8(); }
        BAR();
    }

    // ---------------- epilogue ----------------
    const int region = n0 >> 10;          // 0=q, 1=k, 2=v
    const int cbase = n0 & 1023;
    if (region == 0) {
        #pragma unroll
        for (int mi = 0; mi < 8; mi++) {
            #pragma unroll
            for (int r = 0; r < 4; r++) {
                const int gm = m0 + wm + mi * 16 + quad * 4 + r;
                unsigned short* qr = qws + (size_t)gm * D_ + cbase + wn + ln16;
                #pragma unroll
                for (int ni = 0; ni < 4; ni++)
                    qr[ni * 16] = f2bf(fast_sigmoid(acc[mi][ni][r]));
            }
        }
    } else {
        unsigned short* ShT = (unsigned short*)smem;     // [128 feat][stride 264]
        unsigned short* dstT = (region == 1) ? kT : vT;
        const int bb = m0 >> 13;
        const int ntok0 = m0 & 8191;
        const int hbase = cbase >> 7;
        #pragma unroll
        for (int pp = 0; pp < 2; pp++) {                  // feature-half pass
            __syncthreads();
            if (((wn >> 7) & 1) == pp) {
                #pragma unroll
                for (int mi = 0; mi < 8; mi++) {
                    const int tok0 = wm + mi * 16 + quad * 4;
                    int mk0 = 0, mk1 = 0, mk2 = 0, mk3 = 0;
                    if (region == 1) {
                        mk0 = mask[m0 + tok0];
                        mk1 = mask[m0 + tok0 + 1];
                        mk2 = mask[m0 + tok0 + 2];
                        mk3 = mask[m0 + tok0 + 3];
                    }
                    #pragma unroll
                    for (int ni = 0; ni < 4; ni++) {
                        const int flp = (wn & 127) + ni * 16 + ln16;
                        float v0 = acc[mi][ni][0], v1 = acc[mi][ni][1];
                        float v2 = acc[mi][ni][2], v3 = acc[mi][ni][3];
                        if (region == 1) {
                            v0 = mk0 ? 0.0f : fast_tanh(v0);
                            v1 = mk1 ? 0.0f : fast_tanh(v1);
                            v2 = mk2 ? 0.0f : fast_tanh(v2);
                            v3 = mk3 ? 0.0f : fast_tanh(v3);
                        }
                        ushort4 pk;
                        pk.x = f2bf(v0); pk.y = f2bf(v1); pk.z = f2bf(v2); pk.w = f2bf(v3);
                        *(ushort4*)&ShT[flp * 264 + tok0] = pk;
                    }
                }
            }
            __syncthreads();
            const int h = hbase + pp;
            unsigned short* dstBase = dstT + ((size_t)(bb * 8 + h) * 128) * 8192 + ntok0;
            #pragma unroll
            for (int itc = 0; itc < 8; itc++) {
                const int idx = itc * 512 + t;
                const int fl = idx >> 5, ch = idx & 31;
                uint4 u = *(const uint4*)&ShT[fl * 264 + ch * 8];
                *(uint4*)(dstBase + (size_t)fl * 8192 + ch * 8) = u;
            }
        }
    }
}

#undef STAGE
#undef LDA
#undef LDB
#undef MFMAQ
#undef BAR
#undef VM8
#undef VM0

// ---------------- Kernel 4: kv[bh][d][e] = sum_n kT[d][n]*vT[e][n] (MFMA) -----
__global__ __launch_bounds__(256) void kv_mfma(const unsigned short* __restrict__ kT,
                                               const unsigned short* __restrict__ vT,
                                               float* __restrict__ kv) {
    __shared__ unsigned short As[128 * 32];   // kT rows (d)
    __shared__ unsigned short Bs[128 * 32];   // vT rows (e)
    const int t = threadIdx.x;
    const int w = t >> 6, l = t & 63;
    const int quad = l >> 4, ln16 = l & 15;
    const int bh = blockIdx.y;
    const int kc0 = blockIdx.x * 512;
    const int wm = (w >> 1) * 64, wn = (w & 1) * 64;

    f32x4 acc[4][4] = {};

    const size_t base = (size_t)bh * 128 * 8192;
    const unsigned short* aG = kT + base + (size_t)(w * 16 + (l >> 2)) * 8192
                               + (l & 3) * 8 + kc0;
    const unsigned short* bG = vT + base + (size_t)(w * 16 + (l >> 2)) * 8192
                               + (l & 3) * 8 + kc0;
    char* AsB = (char*)As;
    char* BsB = (char*)Bs;
    char* aL0 = AsB + w * 1024;
    char* aL1 = AsB + 4096 + w * 1024;
    char* bL0 = BsB + w * 1024;
    char* bL1 = BsB + 4096 + w * 1024;

    for (int kk = 0; kk < 512; kk += 32) {
        gl_lds16(aG + kk, aL0);
        gl_lds16(aG + 64 * 8192 + kk, aL1);
        gl_lds16(bG + kk, bL0);
        gl_lds16(bG + 64 * 8192 + kk, bL1);
        __syncthreads();
        bf16x8 af[4], bfr[4];
        #pragma unroll
        for (int mi = 0; mi < 4; mi++)
            af[mi] = *(const bf16x8*)(AsB + (wm + mi * 16 + ln16) * 64 + quad * 16);
        #pragma unroll
        for (int ni = 0; ni < 4; ni++)
            bfr[ni] = *(const bf16x8*)(BsB + (wn + ni * 16 + ln16) * 64 + quad * 16);
        #pragma unroll
        for (int mi = 0; mi < 4; mi++)
            #pragma unroll
            for (int ni = 0; ni < 4; ni++)
                acc[mi][ni] = __builtin_amdgcn_mfma_f32_16x16x32_bf16(af[mi], bfr[ni],
                                                                      acc[mi][ni], 0, 0, 0);
        __syncthreads();
    }

    float* dst = kv + (size_t)bh * (HD_ * HD_);
    #pragma unroll
    for (int mi = 0; mi < 4; mi++) {
        #pragma unroll
        for (int r = 0; r < 4; r++) {
            int d = wm + mi * 16 + quad * 4 + r;   // C/D row
            #pragma unroll
            for (int ni = 0; ni < 4; ni++) {
                int e = wn + ni * 16 + ln16;       // C/D col (consecutive lanes)
                atomicAdd(&dst[d * HD_ + e], acc[mi][ni][r]);
            }
        }
    }
}

// ---------------- Kernel 4b: kv fp32 [bh][d][e] -> kvTb bf16 [bh][e][d] -------
__global__ __launch_bounds__(256) void kvcvt(const float* __restrict__ kv,
                                             unsigned short* __restrict__ kvTb) {
    __shared__ float tile[32][132];
    const int bh = blockIdx.x;
    const int c = blockIdx.y;     // d-chunk of 32
    const int t = threadIdx.x;
    {
        int r = t >> 3, cc = (t & 7) * 16;
        const float* src = kv + ((size_t)bh * 128 + c * 32 + r) * 128 + cc;
        #pragma unroll
        for (int q4 = 0; q4 < 4; q4++)
            *(float4*)&tile[r][cc + q4 * 4] = *(const float4*)(src + q4 * 4);
    }
    __syncthreads();
    {
        int e = t >> 1, dh = t & 1;
        ushort4 o[4];
        #pragma unroll
        for (int q4 = 0; q4 < 4; q4++) {
            o[q4].x = f2bf(tile[dh * 16 + q4 * 4 + 0][e]);
            o[q4].y = f2bf(tile[dh * 16 + q4 * 4 + 1][e]);
            o[q4].z = f2bf(tile[dh * 16 + q4 * 4 + 2][e]);
            o[q4].w = f2bf(tile[dh * 16 + q4 * 4 + 3][e]);
        }
        unsigned short* dst = kvTb + (size_t)bh * 16384 + e * 128 + c * 32 + dh * 16;
        #pragma unroll
        for (int q4 = 0; q4 < 4; q4++)
            ((ushort4*)dst)[q4] = o[q4];
    }
}

// ---------------- Kernel 5: out[tok][h*128+e] = sum_d q[tok][h*128+d]*kvT[e][d]
__global__ __launch_bounds__(256) void out_mfma(const unsigned short* __restrict__ qws,
                                                const unsigned short* __restrict__ kvTb,
                                                float* __restrict__ out) {
    __shared__ unsigned short As[128 * 32];
    __shared__ unsigned short Bs[128 * 32];
    const int t = threadIdx.x;
    const int w = t >> 6, l = t & 63;
    const int quad = l >> 4, ln16 = l & 15;
    const int m0 = blockIdx.x * 128;
    const int h = blockIdx.y;
    const int b = m0 >> 13;
    const int bh = b * 8 + h;
    const int wm = (w >> 1) * 64, wn = (w & 1) * 64;

    f32x4 acc[4][4] = {};

    const unsigned short* aG = qws + (size_t)(m0 + w * 16 + (l >> 2)) * D_
                               + h * HD_ + (l & 3) * 8;
    const unsigned short* bG = kvTb + (size_t)bh * 16384
                               + (size_t)(w * 16 + (l >> 2)) * 128 + (l & 3) * 8;
    char* AsB = (char*)As;
    char* BsB = (char*)Bs;

    for (int kk = 0; kk < 128; kk += 32) {
        gl_lds16(aG + kk, AsB + w * 1024);
        gl_lds16(aG + 64 * D_ + kk, AsB + 4096 + w * 1024);
        gl_lds16(bG + kk, BsB + w * 1024);
        gl_lds16(bG + 64 * 128 + kk, BsB + 4096 + w * 1024);
        __syncthreads();
        bf16x8 af[4], bfr[4];
        #pragma unroll
        for (int mi = 0; mi < 4; mi++)
            af[mi] = *(const bf16x8*)(AsB + (wm + mi * 16 + ln16) * 64 + quad * 16);
        #pragma unroll
        for (int ni = 0; ni < 4; ni++)
            bfr[ni] = *(const bf16x8*)(BsB + (wn + ni * 16 + ln16) * 64 + quad * 16);
        #pragma unroll
        for (int mi = 0; mi < 4; mi++)
            #pragma unroll
            for (int ni = 0; ni < 4; ni++)
                acc[mi][ni] = __builtin_amdgcn_mfma_f32_16x16x32_bf16(af[mi], bfr[ni],
                                                                      acc[mi][ni], 0, 0, 0);
        __syncthreads();
    }

    #pragma unroll
    for (int mi = 0; mi < 4; mi++) {
        #pragma unroll
        for (int r = 0; r < 4; r++) {
            int gm = m0 + wm + mi * 16 + quad * 4 + r;
            #pragma unroll
            for (int ni = 0; ni < 4; ni++) {
                int e = wn + ni * 16 + ln16;
                out[(size_t)gm * D_ + h * HD_ + e] = acc[mi][ni][r];
            }
        }
    }
}

// ---------------- launch ----------------
extern "C" void kernel_launch(void* const* d_in, const int* in_sizes, int n_in,
                              void* d_out, int out_size, void* d_ws, size_t ws_size,
                              hipStream_t stream) {
    const float* x     = (const float*)d_in[0];
    const int*   mask  = (const int*)d_in[1];
    const float* w     = (const float*)d_in[2];
    const float* gamma = (const float*)d_in[3];
    const float* beta  = (const float*)d_in[4];
    float* out = (float*)d_out;
    char* ws = (char*)d_ws;

    // workspace layout (total ~267 MB)
    unsigned short* xn  = (unsigned short*)(ws + 0);              // 64 MB
    unsigned short* wT  = (unsigned short*)(ws + 67108864ull);    // 6 MB
    unsigned short* qws = (unsigned short*)(ws + 73400320ull);    // 64 MB
    unsigned short* kT  = (unsigned short*)(ws + 140509184ull);   // 64 MB [bh][128][8192]
    unsigned short* vT  = (unsigned short*)(ws + 207618048ull);   // 64 MB [bh][128][8192]
    float* kv           = (float*)(ws + 274726912ull);            // 2 MB fp32 [bh][d][e]
    unsigned short* kvTb = (unsigned short*)(ws + 276824064ull);  // 1 MB bf16 [bh][e][d]

    hipMemsetAsync(kv, 0, 32 * HD_ * HD_ * sizeof(float), stream);
    hipLaunchKernelGGL(ln_kernel, dim3(M_TOT), dim3(256), 0, stream, x, gamma, beta, xn);
    hipLaunchKernelGGL(wt_kernel, dim3(48, 16), dim3(256), 0, stream, w, wT);
    hipLaunchKernelGGL(qkv_gemm, dim3(1536), dim3(512), 0, stream,
                       xn, wT, mask, qws, kT, vT);
    hipLaunchKernelGGL(kv_mfma, dim3(16, 32), dim3(256), 0, stream, kT, vT, kv);
    hipLaunchKernelGGL(kvcvt, dim3(32, 4), dim3(256), 0, stream, kv, kvTb);
    hipLaunchKernelGGL(out_mfma, dim3(M_TOT / 128, 8), dim3(256), 0, stream,
                       qws, kvTb, out);
}

// Round 3
// 524.054 us; speedup vs baseline: 1.0748x; 1.0748x over previous
//
#include <hip/hip_runtime.h>

// Problem constants
#define EPS 1e-5f
#define B_ 4
#define N_ 8192
#define D_ 1024
#define H_ 8
#define HD_ 128
#define M_TOT 32768   // B*N
#define NQKV 3072     // 3*D

typedef __bf16 bf16x8 __attribute__((ext_vector_type(8)));
typedef float f32x4 __attribute__((ext_vector_type(4)));

__device__ __forceinline__ float bf2f(unsigned short u) {
    unsigned int v = ((unsigned int)u) << 16;
    return __uint_as_float(v);
}
__device__ __forceinline__ unsigned short f2bf(float f) {
    unsigned int u = __float_as_uint(f);
    u += 0x7fffu + ((u >> 16) & 1u);   // RNE
    return (unsigned short)(u >> 16);
}

// fast activations: v_exp_f32 + v_rcp_f32 (~1e-6 rel err, saturates correctly)
__device__ __forceinline__ float fast_sigmoid(float v) {
    return __builtin_amdgcn_rcpf(1.0f + __expf(-v));
}
__device__ __forceinline__ float fast_tanh(float v) {
    return 1.0f - 2.0f * __builtin_amdgcn_rcpf(1.0f + __expf(2.0f * v));
}

// async global->LDS, 16B per lane; LDS dest is wave-uniform base + lane*16
__device__ __forceinline__ void gl_lds16(const void* g, void* l) {
    __builtin_amdgcn_global_load_lds(
        (const __attribute__((address_space(1))) unsigned int*)g,
        (__attribute__((address_space(3))) unsigned int*)l, 16, 0, 0);
}

// ---------------- Kernel 1: LayerNorm -> bf16 xn [32768][1024] ----------------
// One wave per row, 16 elems/lane, register-only shfl reduction (no LDS, no bar).
__global__ __launch_bounds__(64) void ln_kernel(const float* __restrict__ x,
                                                const float* __restrict__ gamma,
                                                const float* __restrict__ beta,
                                                unsigned short* __restrict__ xn) {
    const int row = blockIdx.x;
    const int t = threadIdx.x;   // 0..63
    const float* xr = x + (size_t)row * D_;
    float4 xv[4];
    #pragma unroll
    for (int i = 0; i < 4; i++) xv[i] = ((const float4*)xr)[i * 64 + t];
    float s = 0.0f, s2 = 0.0f;
    #pragma unroll
    for (int i = 0; i < 4; i++) {
        s  += xv[i].x + xv[i].y + xv[i].z + xv[i].w;
        s2 += xv[i].x * xv[i].x + xv[i].y * xv[i].y
            + xv[i].z * xv[i].z + xv[i].w * xv[i].w;
    }
    #pragma unroll
    for (int off = 32; off > 0; off >>= 1) {
        s  += __shfl_down(s, off);
        s2 += __shfl_down(s2, off);
    }
    s = __shfl(s, 0);
    s2 = __shfl(s2, 0);
    const float mu = s * (1.0f / D_);
    const float var = s2 * (1.0f / D_) - mu * mu;
    const float rs = rsqrtf(var + EPS);
    unsigned short* xo = xn + (size_t)row * D_;
    #pragma unroll
    for (int i = 0; i < 4; i++) {
        float4 g  = ((const float4*)gamma)[i * 64 + t];
        float4 bt = ((const float4*)beta)[i * 64 + t];
        ushort4 o;
        o.x = f2bf((xv[i].x - mu) * rs * g.x + bt.x);
        o.y = f2bf((xv[i].y - mu) * rs * g.y + bt.y);
        o.z = f2bf((xv[i].z - mu) * rs * g.z + bt.z);
        o.w = f2bf((xv[i].w - mu) * rs * g.w + bt.w);
        ((ushort4*)xo)[i * 64 + t] = o;
    }
}

// ---------------- Kernel 2: transpose+cast w [1024][3072] -> wT bf16 [3072][1024]
__global__ __launch_bounds__(256) void wt_kernel(const float* __restrict__ w,
                                                 unsigned short* __restrict__ wT) {
    __shared__ float tile[64][65];
    const int n0 = blockIdx.x * 64;   // 48 blocks
    const int k0 = blockIdx.y * 64;   // 16 blocks
    const int t = threadIdx.x;
    const int tx = t & 63, ty = t >> 6;
    #pragma unroll
    for (int i = 0; i < 16; i++) {
        int r = i * 4 + ty;
        tile[r][tx] = w[(size_t)(k0 + r) * NQKV + n0 + tx];
    }
    __syncthreads();
    #pragma unroll
    for (int i = 0; i < 16; i++) {
        int r = i * 4 + ty;
        wT[(size_t)(n0 + r) * D_ + k0 + tx] = f2bf(tile[tx][r]);
    }
}

// ---------------- Kernel 3: fused QKV GEMM (bf16 MFMA) + activations ----------
// (reverted to the proven 228-us round-0 structure, byte-identical)
#define CT_STRIDE 136
__global__ __launch_bounds__(256, 3) void qkv_gemm(const unsigned short* __restrict__ xn,
                                                   const unsigned short* __restrict__ wT,
                                                   const int* __restrict__ mask,
                                                   unsigned short* __restrict__ qws,
                                                   unsigned short* __restrict__ kT,
                                                   unsigned short* __restrict__ vT) {
    __shared__ unsigned short ShB[128 * CT_STRIDE];   // 34816 B; mainloop uses 32 KB
    const int t = threadIdx.x;
    const int w = t >> 6, l = t & 63;
    const int quad = l >> 4, ln16 = l & 15;
    const int m0 = blockIdx.y * 128;
    const int n0 = blockIdx.x * 128;
    const int wm = (w >> 1) * 64, wn = (w & 1) * 64;

    f32x4 acc[4][4] = {};

    const unsigned short* aG = xn + (size_t)(m0 + w * 16 + (l >> 2)) * D_ + (l & 3) * 8;
    const unsigned short* bG = wT + (size_t)(n0 + w * 16 + (l >> 2)) * D_ + (l & 3) * 8;
    char* SB = (char*)ShB;
    // staging layout: A stage s at SB + s*8192 (two 4KB halves); B at +16384.

    for (int k0 = 0; k0 < 1024; k0 += 64) {
        #pragma unroll
        for (int s = 0; s < 2; s++) {
            gl_lds16(aG + k0 + s * 32,            SB + s * 8192 + w * 1024);
            gl_lds16(aG + 64 * D_ + k0 + s * 32,  SB + s * 8192 + 4096 + w * 1024);
            gl_lds16(bG + k0 + s * 32,            SB + 16384 + s * 8192 + w * 1024);
            gl_lds16(bG + 64 * D_ + k0 + s * 32,  SB + 16384 + s * 8192 + 4096 + w * 1024);
        }
        __syncthreads();   // drains vmcnt for global_load_lds
        #pragma unroll
        for (int s = 0; s < 2; s++) {
            const char* A0 = SB + s * 8192;
            const char* B0 = SB + 16384 + s * 8192;
            bf16x8 af[4], bfr[4];
            #pragma unroll
            for (int mi = 0; mi < 4; mi++)
                af[mi] = *(const bf16x8*)(A0 + (wm + mi * 16 + ln16) * 64 + quad * 16);
            #pragma unroll
            for (int ni = 0; ni < 4; ni++)
                bfr[ni] = *(const bf16x8*)(B0 + (wn + ni * 16 + ln16) * 64 + quad * 16);
            #pragma unroll
            for (int mi = 0; mi < 4; mi++)
                #pragma unroll
                for (int ni = 0; ni < 4; ni++)
                    acc[mi][ni] = __builtin_amdgcn_mfma_f32_16x16x32_bf16(af[mi], bfr[ni],
                                                                          acc[mi][ni], 0, 0, 0);
        }
        __syncthreads();
    }

    // epilogue: region 0=q (sigmoid, token-major), 1=k (tanh+mask, transposed),
    //           2=v (identity, transposed)
    const int region = n0 >> 10;
    const int cbase = n0 & 1023;
    if (region == 0) {
        #pragma unroll
        for (int mi = 0; mi < 4; mi++) {
            #pragma unroll
            for (int r = 0; r < 4; r++) {
                int gm = m0 + wm + mi * 16 + quad * 4 + r;   // C/D row = quad*4+reg
                #pragma unroll
                for (int ni = 0; ni < 4; ni++) {
                    int cc = cbase + wn + ni * 16 + ln16;    // C/D col = lane&15
                    qws[(size_t)gm * D_ + cc] = f2bf(fast_sigmoid(acc[mi][ni][r]));
                }
            }
        }
    } else {
        // phase 1: store tile into LDS transposed [feat][tok], packed 4 toks/write
        #pragma unroll
        for (int mi = 0; mi < 4; mi++) {
            int tok0 = wm + mi * 16 + quad * 4;
            int mk0 = 0, mk1 = 0, mk2 = 0, mk3 = 0;
            if (region == 1) {
                mk0 = mask[m0 + tok0];
                mk1 = mask[m0 + tok0 + 1];
                mk2 = mask[m0 + tok0 + 2];
                mk3 = mask[m0 + tok0 + 3];
            }
            #pragma unroll
            for (int ni = 0; ni < 4; ni++) {
                int fl = wn + ni * 16 + ln16;
                float v0 = acc[mi][ni][0], v1 = acc[mi][ni][1];
                float v2 = acc[mi][ni][2], v3 = acc[mi][ni][3];
                if (region == 1) {
                    v0 = mk0 ? 0.0f : fast_tanh(v0);
                    v1 = mk1 ? 0.0f : fast_tanh(v1);
                    v2 = mk2 ? 0.0f : fast_tanh(v2);
                    v3 = mk3 ? 0.0f : fast_tanh(v3);
                }
                ushort4 pk;
                pk.x = f2bf(v0); pk.y = f2bf(v1); pk.z = f2bf(v2); pk.w = f2bf(v3);
                *(ushort4*)&ShB[fl * CT_STRIDE + tok0] = pk;   // 8B-aligned ds_write_b64
            }
        }
        __syncthreads();
        // phase 2: coalesced transposed global write (256B per feature row)
        unsigned short* dstT = (region == 1) ? kT : vT;
        const int h = cbase >> 7;          // block covers exactly one head
        const int b = m0 >> 13;
        const int ntok0 = m0 & 8191;
        #pragma unroll
        for (int p = 0; p < 8; p++) {
            int fl = p * 16 + (t >> 4);
            int tok = (t & 15) * 8;
            uint4 u = *(const uint4*)&ShB[fl * CT_STRIDE + tok];   // 16B-aligned b128
            *(uint4*)(dstT + ((size_t)(b * 8 + h) * 128 + fl) * 8192 + ntok0 + tok) = u;
        }
    }
}

// ---------------- Kernel 4: kv partials: kvp[kc][bh][d][e] = sum_{n in chunk} kT[d][n]*vT[e][n]
// BK=64, XOR-swizzled LDS (granule ^= row&7) for conflict-free b128 fragment
// reads; per-(chunk,bh) partial tiles (no atomics). grid (16 chunks, 32 bh).
__global__ __launch_bounds__(256) void kv_mfma(const unsigned short* __restrict__ kT,
                                               const unsigned short* __restrict__ vT,
                                               float* __restrict__ kvp) {
    __shared__ __align__(16) char smem[32768];   // A 16KB + B 16KB
    char* AsB = smem;
    char* BsB = smem + 16384;
    const int t = threadIdx.x;
    const int w = t >> 6, l = t & 63;
    const int quad = l >> 4, ln16 = l & 15;
    const int bh = blockIdx.y;
    const int kc0 = blockIdx.x * 512;
    const int wm = (w >> 1) * 64, wn = (w & 1) * 64;

    f32x4 acc[4][4] = {};

    const size_t base = (size_t)bh * 128 * 8192;
    // staging: row = c*32 + w*8 + (l>>3); LDS row stride 128 B (8 granules of 16 B)
    // pre-swizzled source granule: (l&7) ^ (row&7), row&7 == l>>3
    const int gsw = (l & 7) ^ (l >> 3);
    const unsigned short* aG = kT + base + (size_t)(w * 8 + (l >> 3)) * 8192 + kc0 + gsw * 8;
    const unsigned short* bG = vT + base + (size_t)(w * 8 + (l >> 3)) * 8192 + kc0 + gsw * 8;
    // fragment read byte offsets within the 128-B row, swizzled by row&7 == ln16&7
    const int r7 = ln16 & 7;
    const int kb0 = ((quad ^ r7) << 4);
    const int kb1 = (((4 | quad) ^ r7) << 4);

    for (int kk = 0; kk < 512; kk += 64) {
        #pragma unroll
        for (int c = 0; c < 4; c++) {
            gl_lds16(aG + (size_t)(c * 32) * 8192 + kk, AsB + c * 4096 + w * 1024);
            gl_lds16(bG + (size_t)(c * 32) * 8192 + kk, BsB + c * 4096 + w * 1024);
        }
        __syncthreads();
        bf16x8 af[4][2], bfr[4][2];
        #pragma unroll
        for (int mi = 0; mi < 4; mi++) {
            const char* rp = AsB + (wm + mi * 16 + ln16) * 128;
            af[mi][0] = *(const bf16x8*)(rp + kb0);
            af[mi][1] = *(const bf16x8*)(rp + kb1);
        }
        #pragma unroll
        for (int ni = 0; ni < 4; ni++) {
            const char* rp = BsB + (wn + ni * 16 + ln16) * 128;
            bfr[ni][0] = *(const bf16x8*)(rp + kb0);
            bfr[ni][1] = *(const bf16x8*)(rp + kb1);
        }
        #pragma unroll
        for (int mi = 0; mi < 4; mi++)
            #pragma unroll
            for (int ni = 0; ni < 4; ni++) {
                acc[mi][ni] = __builtin_amdgcn_mfma_f32_16x16x32_bf16(af[mi][0], bfr[ni][0],
                                                                      acc[mi][ni], 0, 0, 0);
                acc[mi][ni] = __builtin_amdgcn_mfma_f32_16x16x32_bf16(af[mi][1], bfr[ni][1],
                                                                      acc[mi][ni], 0, 0, 0);
            }
        __syncthreads();
    }

    float* dst = kvp + ((size_t)blockIdx.x * 32 + bh) * (HD_ * HD_);
    #pragma unroll
    for (int mi = 0; mi < 4; mi++) {
        #pragma unroll
        for (int r = 0; r < 4; r++) {
            int d = wm + mi * 16 + quad * 4 + r;
            #pragma unroll
            for (int ni = 0; ni < 4; ni++) {
                int e = wn + ni * 16 + ln16;
                dst[d * HD_ + e] = acc[mi][ni][r];
            }
        }
    }
}

// ---------------- Kernel 4b: reduce 16 partials + transpose + cast -> kvTb bf16 [bh][e][d]
__global__ __launch_bounds__(256) void kvcvt(const float* __restrict__ kvp,
                                             unsigned short* __restrict__ kvTb) {
    __shared__ float tile[32][132];
    const int bh = blockIdx.x;
    const int c = blockIdx.y;     // d-chunk of 32
    const int t = threadIdx.x;
    {
        int r = t >> 3, cc = (t & 7) * 16;
        f32x4 s[4] = {};
        for (int p = 0; p < 16; p++) {
            const float* src = kvp + ((size_t)p * 32 + bh) * (HD_ * HD_)
                               + (size_t)(c * 32 + r) * 128 + cc;
            #pragma unroll
            for (int q4 = 0; q4 < 4; q4++)
                s[q4] += *(const f32x4*)(src + q4 * 4);
        }
        #pragma unroll
        for (int q4 = 0; q4 < 4; q4++)
            *(f32x4*)&tile[r][cc + q4 * 4] = s[q4];
    }
    __syncthreads();
    {
        int e = t >> 1, dh = t & 1;
        ushort4 o[4];
        #pragma unroll
        for (int q4 = 0; q4 < 4; q4++) {
            o[q4].x = f2bf(tile[dh * 16 + q4 * 4 + 0][e]);
            o[q4].y = f2bf(tile[dh * 16 + q4 * 4 + 1][e]);
            o[q4].z = f2bf(tile[dh * 16 + q4 * 4 + 2][e]);
            o[q4].w = f2bf(tile[dh * 16 + q4 * 4 + 3][e]);
        }
        unsigned short* dst = kvTb + (size_t)bh * 16384 + e * 128 + c * 32 + dh * 16;
        #pragma unroll
        for (int q4 = 0; q4 < 4; q4++)
            ((ushort4*)dst)[q4] = o[q4];
    }
}

// ---------------- Kernel 5: out = q . kv  (single-stage: K=128 fits LDS) ------
// Both 128x128 bf16 tiles staged once (XOR-swizzled, granule ^= row&15),
// ONE barrier, ks-loop keeps live registers low. fp32 output.
__global__ __launch_bounds__(256) void out_mfma(const unsigned short* __restrict__ qws,
                                                const unsigned short* __restrict__ kvTb,
                                                float* __restrict__ out) {
    __shared__ __align__(16) char smem[65536];   // A 32KB + B 32KB
    char* AsB = smem;
    char* BsB = smem + 32768;
    const int t = threadIdx.x;
    const int w = t >> 6, l = t & 63;
    const int quad = l >> 4, ln16 = l & 15;
    const int m0 = blockIdx.x * 128;
    const int h = blockIdx.y;
    const int b = m0 >> 13;
    const int bh = b * 8 + h;
    const int wm = (w >> 1) * 64, wn = (w & 1) * 64;

    // staging: row = c*16 + w*4 + (l>>4); LDS row stride 256 B (16 granules).
    // pre-swizzled source granule: (l&15) ^ (row&15), row&15 == w*4 + (l>>4)
    const int gsw = (l & 15) ^ (w * 4 + (l >> 4));
    const unsigned short* aG = qws + (size_t)(m0 + w * 4 + (l >> 4)) * D_
                               + h * HD_ + gsw * 8;
    const unsigned short* bG = kvTb + (size_t)bh * 16384
                               + (size_t)(w * 4 + (l >> 4)) * 128 + gsw * 8;
    #pragma unroll
    for (int c = 0; c < 8; c++) {
        gl_lds16(aG + (size_t)(c * 16) * D_, AsB + c * 4096 + w * 1024);
        gl_lds16(bG + (c * 16) * 128,        BsB + c * 4096 + w * 1024);
    }
    __syncthreads();   // drains vmcnt for global_load_lds

    f32x4 acc[4][4] = {};
    #pragma unroll
    for (int ks = 0; ks < 4; ks++) {
        bf16x8 af[4], bfr[4];
        #pragma unroll
        for (int mi = 0; mi < 4; mi++)
            af[mi] = *(const bf16x8*)(AsB + (wm + mi * 16 + ln16) * 256
                                      + ((((ks * 4) + quad) ^ ln16) << 4));
        #pragma unroll
        for (int ni = 0; ni < 4; ni++)
            bfr[ni] = *(const bf16x8*)(BsB + (wn + ni * 16 + ln16) * 256
                                       + ((((ks * 4) + quad) ^ ln16) << 4));
        #pragma unroll
        for (int mi = 0; mi < 4; mi++)
            #pragma unroll
            for (int ni = 0; ni < 4; ni++)
                acc[mi][ni] = __builtin_amdgcn_mfma_f32_16x16x32_bf16(af[mi], bfr[ni],
                                                                      acc[mi][ni], 0, 0, 0);
    }

    #pragma unroll
    for (int mi = 0; mi < 4; mi++) {
        #pragma unroll
        for (int r = 0; r < 4; r++) {
            int gm = m0 + wm + mi * 16 + quad * 4 + r;
            #pragma unroll
            for (int ni = 0; ni < 4; ni++) {
                int e = wn + ni * 16 + ln16;
                out[(size_t)gm * D_ + h * HD_ + e] = acc[mi][ni][r];
            }
        }
    }
}

// ---------------- launch ----------------
extern "C" void kernel_launch(void* const* d_in, const int* in_sizes, int n_in,
                              void* d_out, int out_size, void* d_ws, size_t ws_size,
                              hipStream_t stream) {
    const float* x     = (const float*)d_in[0];
    const int*   mask  = (const int*)d_in[1];
    const float* w     = (const float*)d_in[2];
    const float* gamma = (const float*)d_in[3];
    const float* beta  = (const float*)d_in[4];
    float* out = (float*)d_out;
    char* ws = (char*)d_ws;

    // workspace layout (~276 MB)
    unsigned short* xn  = (unsigned short*)(ws + 0);              // 64 MB (dead after qkv)
    unsigned short* wT  = (unsigned short*)(ws + 67108864ull);    // 6 MB
    unsigned short* qws = (unsigned short*)(ws + 73400320ull);    // 64 MB
    unsigned short* kT  = (unsigned short*)(ws + 140509184ull);   // 64 MB [bh][128][8192]
    unsigned short* vT  = (unsigned short*)(ws + 207618048ull);   // 64 MB [bh][128][8192]
    unsigned short* kvTb = (unsigned short*)(ws + 274726912ull);  // 1 MB bf16 [bh][e][d]
    // kv partials reuse the (dead-by-then) xn region: 16*32*128*128*4 = 32 MB
    float* kvp = (float*)(ws + 0);

    hipLaunchKernelGGL(ln_kernel, dim3(M_TOT), dim3(64), 0, stream, x, gamma, beta, xn);
    hipLaunchKernelGGL(wt_kernel, dim3(48, 16), dim3(256), 0, stream, w, wT);
    hipLaunchKernelGGL(qkv_gemm, dim3(NQKV / 128, M_TOT / 128), dim3(256), 0, stream,
                       xn, wT, mask, qws, kT, vT);
    hipLaunchKernelGGL(kv_mfma, dim3(16, 32), dim3(256), 0, stream, kT, vT, kvp);
    hipLaunchKernelGGL(kvcvt, dim3(32, 4), dim3(256), 0, stream, kvp, kvTb);
    hipLaunchKernelGGL(out_mfma, dim3(M_TOT / 128, 8), dim3(256), 0, stream,
                       qws, kvTb, out);
}